// Round 1
// baseline (351.292 us; speedup 1.0000x reference)
//
#include <hip/hip_runtime.h>
#include <hip/hip_bf16.h>
#include <math.h>

// Problem constants
#define NQ1 1001      // NQ+1 rows in embed tables
#define KK 5
#define MM 50
#define KD 64
#define VD 64
#define SD 50
#define BB 512
#define SS 500

// Workspace layout (in floats)
#define OFF_ATTN   0                      // [1001][64]  attn rows, padded to 64
#define OFF_SQ     (OFF_ATTN + NQ1*64)    // [1001][64]  q_embed @ Ws[64:128], padded
#define OFF_ETAB   (OFF_SQ   + NQ1*64)    // [5005][64]
#define OFF_ADTAB  (OFF_ETAB + NQ1*KK*64) // [5005][64]
#define OFF_WST    (OFF_ADTAB+ NQ1*KK*64) // [50][64] transposed top of Ws
#define OFF_WCT    (OFF_WST  + SD*64)     // [5][50] transposed Wc (pad to 256)
#define OFF_READS  (OFF_WCT  + 256)       // [512*500][64]

// ---------------- kernel 0: transposes ----------------
__global__ __launch_bounds__(256) void k_transpose(
    const float* __restrict__ Ws, const float* __restrict__ Wc,
    float* __restrict__ WsT, float* __restrict__ WcT) {
  int t = threadIdx.x;
  for (int idx = t; idx < 64 * SD; idx += 256) {
    int i = idx / SD, j = idx % SD;          // Ws[i][j], i<64 (read part)
    WsT[j * 64 + i] = Ws[idx];
  }
  for (int idx = t; idx < SD * KK; idx += 256) {
    int j = idx / KK, c = idx % KK;          // Wc[j][c]
    WcT[c * SD + j] = Wc[idx];
  }
}

// ---------------- kernel 1: per-question tables (attn softmax + Sq) ----------------
__global__ __launch_bounds__(64) void k_qtab(
    const float* __restrict__ qtab, const float* __restrict__ keymem,
    const float* __restrict__ Ws,
    float* __restrict__ attn_tab, float* __restrict__ sq_tab) {
  const int q = blockIdx.x;
  const int t = threadIdx.x;
  __shared__ float qe[64];
  qe[t] = qtab[q * KD + t];
  __syncthreads();

  float dot = 0.f;
  if (t < MM) {
#pragma unroll
    for (int i = 0; i < KD; ++i) dot = fmaf(qe[i], keymem[t * KD + i], dot);
  }
  float xv = (t < MM) ? dot : -1e30f;
#pragma unroll
  for (int off = 32; off; off >>= 1) xv = fmaxf(xv, __shfl_xor(xv, off));
  float p = (t < MM) ? __expf(dot - xv) : 0.f;
  float sum = p;
#pragma unroll
  for (int off = 32; off; off >>= 1) sum += __shfl_xor(sum, off);
  attn_tab[q * 64 + t] = p / sum;   // pad lanes (t>=50) write 0

  float sq = 0.f;
  if (t < SD) {
#pragma unroll
    for (int i = 0; i < KD; ++i) sq = fmaf(qe[i], Ws[(64 + i) * SD + t], sq);
  }
  sq_tab[q * 64 + t] = (t < SD) ? sq : 0.f;
}

// ---------------- kernel 2: per-(q,r) erase/add tables ----------------
__global__ __launch_bounds__(64) void k_evtab(
    const float* __restrict__ itab, const float* __restrict__ Wv,
    const float* __restrict__ bv, const float* __restrict__ We,
    const float* __restrict__ be, const float* __restrict__ Wa,
    const float* __restrict__ ba,
    float* __restrict__ e_tab, float* __restrict__ ad_tab) {
  const int qr = blockIdx.x;
  const int q = qr / KK, r = qr % KK;
  const int v = threadIdx.x;
  __shared__ float item[64];
  __shared__ float ves[64];
  item[v] = itab[q * KD + v];
  __syncthreads();

  float ve = bv[v];
#pragma unroll
  for (int i = 0; i < KD; ++i) ve = fmaf(item[i], Wv[i * VD + v], ve);
#pragma unroll
  for (int k = 0; k < KK; ++k) {
    float rf = fmaxf(0.f, 1.f - fabsf((float)k - (float)r) * 0.25f);
    ve = fmaf(rf, Wv[(KD + k) * VD + v], ve);
  }
  ves[v] = ve;
  __syncthreads();

  float se = be[v], sa = ba[v];
#pragma unroll
  for (int i = 0; i < VD; ++i) {
    float x = ves[i];
    se = fmaf(x, We[i * VD + v], se);
    sa = fmaf(x, Wa[i * VD + v], sa);
  }
  e_tab[qr * 64 + v] = 1.f / (1.f + __expf(-se));
  float ex = __expf(2.f * sa);
  ad_tab[qr * 64 + v] = (ex - 1.f) / (ex + 1.f);
}

// ---------------- kernel 3: sequential scan, one wave per batch ----------------
__global__ __launch_bounds__(64) void k_scan(
    const int* __restrict__ qs, const int* __restrict__ rs,
    const float* __restrict__ attn_tab, const float* __restrict__ e_tab,
    const float* __restrict__ ad_tab, const float* __restrict__ init_vm,
    float* __restrict__ reads) {
  const int b = blockIdx.x;
  const int v = threadIdx.x;

  float vm[MM];
#pragma unroll
  for (int m = 0; m < MM; ++m) vm[m] = init_vm[m * VD + v];

  const int* __restrict__ qb = qs + b * SS;
  const int* __restrict__ rb = rs + b * SS;

  int q1 = qb[0], r1 = rb[0];
  int q2 = qb[1], r2 = rb[1];
  float e1 = e_tab[(q1 * KK + r1) * 64 + v];
  float ad1 = ad_tab[(q1 * KK + r1) * 64 + v];
  float* outp = reads + ((size_t)b * SS) * 64 + v;

  for (int s = 0; s < SS; ++s) {
    // prefetch next step's e/ad (q2 already resident) and step+2 indices
    float e2 = 0.f, ad2 = 0.f;
    int q3 = 0, r3 = 0;
    if (s + 1 < SS) {
      e2 = e_tab[(q2 * KK + r2) * 64 + v];
      ad2 = ad_tab[(q2 * KK + r2) * 64 + v];
    }
    if (s + 2 < SS) { q3 = qb[s + 2]; r3 = rb[s + 2]; }

    const float* __restrict__ arow = attn_tab + q1 * 64;   // 256B-aligned, uniform
    float acc0 = 0.f, acc1 = 0.f;
#pragma unroll
    for (int m = 0; m < MM; m += 2) {
      float a0 = arow[m];
      float a1 = arow[m + 1];
      acc0 = fmaf(a0, vm[m], acc0);
      vm[m] = fmaf(a0, fmaf(-e1, vm[m], ad1), vm[m]);
      acc1 = fmaf(a1, vm[m + 1], acc1);
      vm[m + 1] = fmaf(a1, fmaf(-e1, vm[m + 1], ad1), vm[m + 1]);
    }
    outp[s * 64] = acc0 + acc1;

    q1 = q2; r1 = r2; e1 = e2; ad1 = ad2;
    q2 = q3; r2 = r3;
  }
}

// ---------------- kernel 4: summary + logits + softmax ----------------
__global__ __launch_bounds__(64) void k_out(
    const float* __restrict__ reads, const int* __restrict__ qs,
    const float* __restrict__ sq_tab, const float* __restrict__ WsT,
    const float* __restrict__ bs, const float* __restrict__ WcT,
    const float* __restrict__ bc,
    float* __restrict__ out_logits, float* __restrict__ out_probs) {
  __shared__ float xs[64 * 65];
  const int lane = threadIdx.x;
  const long rowbase = (long)blockIdx.x * 64;
  const float* __restrict__ src = reads + rowbase * 64;

  // stage 64 rows x 64 cols into LDS with +1 pad (conflict-free row reads)
#pragma unroll 8
  for (int it = 0; it < 64; ++it)
    xs[it * 65 + lane] = src[it * 64 + lane];
  __syncthreads();

  float x[64];
#pragma unroll
  for (int i = 0; i < 64; ++i) x[i] = xs[lane * 65 + i];

  const long row = rowbase + lane;
  const int q = qs[row];
  const float* __restrict__ sqrow = sq_tab + (long)q * 64;

  float sm[SD];
#pragma unroll
  for (int j = 0; j < SD; ++j) {
    float acc = bs[j] + sqrow[j];
    const float* __restrict__ wrow = WsT + j * 64;  // uniform -> s_load
#pragma unroll
    for (int i = 0; i < 64; ++i) acc = fmaf(x[i], wrow[i], acc);
    float ex = __expf(2.f * acc);
    sm[j] = (ex - 1.f) / (ex + 1.f);
  }

  float lg[KK];
#pragma unroll
  for (int c = 0; c < KK; ++c) {
    float acc = bc[c];
    const float* __restrict__ wrow = WcT + c * SD;  // uniform -> s_load
#pragma unroll
    for (int j = 0; j < SD; ++j) acc = fmaf(sm[j], wrow[j], acc);
    lg[c] = acc;
  }

  float mx = lg[0];
#pragma unroll
  for (int c = 1; c < KK; ++c) mx = fmaxf(mx, lg[c]);
  float p[KK], sum = 0.f;
#pragma unroll
  for (int c = 0; c < KK; ++c) { p[c] = __expf(lg[c] - mx); sum += p[c]; }
  float inv = 1.f / sum;
#pragma unroll
  for (int c = 0; c < KK; ++c) {
    out_logits[row * KK + c] = lg[c];
    out_probs[row * KK + c] = p[c] * inv;
  }
}

extern "C" void kernel_launch(void* const* d_in, const int* in_sizes, int n_in,
                              void* d_out, int out_size, void* d_ws, size_t ws_size,
                              hipStream_t stream) {
  const int*   questions  = (const int*)  d_in[0];
  const int*   responses  = (const int*)  d_in[1];
  const float* q_table    = (const float*)d_in[2];
  const float* item_table = (const float*)d_in[3];
  const float* Wv         = (const float*)d_in[4];
  const float* bv         = (const float*)d_in[5];
  const float* key_mem    = (const float*)d_in[6];
  const float* init_vm    = (const float*)d_in[7];
  const float* We         = (const float*)d_in[8];
  const float* be         = (const float*)d_in[9];
  const float* Wa         = (const float*)d_in[10];
  const float* ba         = (const float*)d_in[11];
  const float* Ws         = (const float*)d_in[12];
  const float* bs         = (const float*)d_in[13];
  const float* Wc         = (const float*)d_in[14];
  const float* bc         = (const float*)d_in[15];

  float* ws       = (float*)d_ws;
  float* attn_tab = ws + OFF_ATTN;
  float* sq_tab   = ws + OFF_SQ;
  float* e_tab    = ws + OFF_ETAB;
  float* ad_tab   = ws + OFF_ADTAB;
  float* WsT      = ws + OFF_WST;
  float* WcT      = ws + OFF_WCT;
  float* reads    = ws + OFF_READS;

  float* out_logits = (float*)d_out;
  float* out_probs  = out_logits + (size_t)BB * SS * KK;

  hipLaunchKernelGGL(k_transpose, dim3(1), dim3(256), 0, stream, Ws, Wc, WsT, WcT);
  hipLaunchKernelGGL(k_qtab, dim3(NQ1), dim3(64), 0, stream,
                     q_table, key_mem, Ws, attn_tab, sq_tab);
  hipLaunchKernelGGL(k_evtab, dim3(NQ1 * KK), dim3(64), 0, stream,
                     item_table, Wv, bv, We, be, Wa, ba, e_tab, ad_tab);
  hipLaunchKernelGGL(k_scan, dim3(BB), dim3(64), 0, stream,
                     questions, responses, attn_tab, e_tab, ad_tab, init_vm, reads);
  hipLaunchKernelGGL(k_out, dim3(BB * SS / 64), dim3(64), 0, stream,
                     reads, questions, sq_tab, WsT, bs, WcT, bc,
                     out_logits, out_probs);
}